// Round 5
// baseline (178.911 us; speedup 1.0000x reference)
//
#include <hip/hip_runtime.h>

#define S      4096
#define D      512
#define KWIN   3
#define SP     (S + 2)          // zero-padded rows: g = s + tap, g in [0, S+1]
#define MAXOUT 16384
#define EPSLN  1e-5f
#define NIT    16               // i-tiles per tap (512/32)
#define NKT    48               // total K tiles of 32 (1536/32)
#define KSPLIT 4
#define KQ     (NKT / KSPLIT)   // 12 K32-stages per block

typedef __attribute__((ext_vector_type(8)))  short short8;
typedef __attribute__((ext_vector_type(16))) float floatx16;

__device__ inline ushort f2bf(float x) {
  union { float f; unsigned u; } v; v.f = x;
  unsigned r = v.u + 0x7fffu + ((v.u >> 16) & 1u);
  return (ushort)(r >> 16);
}
__device__ inline float bf2f(ushort h) {
  union { float f; unsigned u; } v; v.u = ((unsigned)h) << 16;
  return v.f;
}

// ---------------------------------------------------------------------------
// One launch does ALL packing (vectorized short8 writes):
//  region 0: enc -> Xp hi/lo [NIT][SP][32], zero pad rows   (1025 blocks)
//  region 1: w1  -> B1 hi/lo [NKT][D][32]                   (384 blocks)
//  region 2: w2  -> B2 hi/lo                                (384 blocks)
//  region 3: zero T1 pad rows                               (4 blocks)
// ---------------------------------------------------------------------------
#define NB0 1025
#define NB1 384
#define NB3 4

__device__ inline void wpack8(const float* __restrict__ w, ushort* __restrict__ bh,
                              ushort* __restrict__ bl, int q) {
  const int kk0 = (q & 3) * 8;
  const int o   = (q >> 2) & 511;
  const int it  = (q >> 11) & 15;
  const int k   = q >> 15;             // 0..2
  short8 h8, l8;
#pragma unroll
  for (int j = 0; j < 8; ++j) {
    const float v = w[o * (D * KWIN) + (it * 32 + kk0 + j) * KWIN + k];
    const ushort hi = f2bf(v);
    h8[j] = (short)hi;
    l8[j] = (short)f2bf(v - bf2f(hi));
  }
  *(short8*)(bh + (size_t)q * 8) = h8;   // dst == q*8 exactly (layout identity)
  *(short8*)(bl + (size_t)q * 8) = l8;
}

__global__ __launch_bounds__(256) void pack_all_kernel(
    const float* __restrict__ x, const float* __restrict__ w1,
    const float* __restrict__ w2, ushort* __restrict__ Xph,
    ushort* __restrict__ Xpl, ushort* __restrict__ B1h, ushort* __restrict__ B1l,
    ushort* __restrict__ B2h, ushort* __restrict__ B2l,
    ushort* __restrict__ T1h, ushort* __restrict__ T1l) {
  const int b = blockIdx.x;
  if (b < NB0) {
    const int t = b * 256 + threadIdx.x;          // over SP*64 groups of 8
    if (t >= SP * 64) return;
    const int g  = t >> 6;
    const int i0 = (t & 63) * 8;
    float vv[8] = {};
    if (g > 0 && g < SP - 1) {
      const float4 v0 = *(const float4*)(x + (size_t)(g - 1) * D + i0);
      const float4 v1 = *(const float4*)(x + (size_t)(g - 1) * D + i0 + 4);
      vv[0] = v0.x; vv[1] = v0.y; vv[2] = v0.z; vv[3] = v0.w;
      vv[4] = v1.x; vv[5] = v1.y; vv[6] = v1.z; vv[7] = v1.w;
    }
    short8 h8, l8;
#pragma unroll
    for (int j = 0; j < 8; ++j) {
      const ushort hi = f2bf(vv[j]);
      h8[j] = (short)hi;
      l8[j] = (short)f2bf(vv[j] - bf2f(hi));
    }
    const size_t dst = ((size_t)(i0 >> 5) * SP + g) * 32 + (i0 & 31);
    *(short8*)(Xph + dst) = h8;
    *(short8*)(Xpl + dst) = l8;
  } else if (b < NB0 + NB1) {
    wpack8(w1, B1h, B1l, (b - NB0) * 256 + threadIdx.x);
  } else if (b < NB0 + 2 * NB1) {
    wpack8(w2, B2h, B2l, (b - NB0 - NB1) * 256 + threadIdx.x);
  } else {
    const int idx = (b - NB0 - 2 * NB1) * 256 + threadIdx.x;   // 0..1023
    const int c   = idx >> 6;
    const int rr  = (idx >> 5) & 1;
    const int col = idx & 31;
    const size_t off = ((size_t)c * SP + (rr ? (SP - 1) : 0)) * 32 + col;
    T1h[off] = 0;
    T1l[off] = 0;
  }
}

// ---------------------------------------------------------------------------
// MFMA GEMM, fp32-accurate bf16 hi/lo (hh+hl+lh), 32x32x16 MFMA.
// Block tile 128x128, 4 waves in 2x2, wave tile 64x64 (2x2 accs of 32x32).
// Split-K=4 via gridDim.z: kt in [z*12, z*12+12), partial to Cp + z*S*D.
// Double-buffered LDS, one barrier/stage.
// LDS layout per array is CHUNK-MAJOR: [chunk 0..3][row 0..127][8 ushorts].
// A fragment read (32 consecutive rows, fixed chunk) is then 32 consecutive
// 16B chunks -> canonical conflict-free ds_read_b128 (wave-halves alias
// 2-way across chunks, which is free). global_load_lds produces this layout
// via per-lane global source addresses (LDS dst stays uniform + lane*16).
// ---------------------------------------------------------------------------
__device__ inline void gload16(const void* g, void* l) {
  __builtin_amdgcn_global_load_lds((const __attribute__((address_space(1))) void*)g,
                                   (__attribute__((address_space(3))) void*)l,
                                   16, 0, 0);
}

__global__ __launch_bounds__(256) void gemm_mfma_kernel(
    const ushort* __restrict__ Ah, const ushort* __restrict__ Al,
    const ushort* __restrict__ Bh, const ushort* __restrict__ Bl,
    float* __restrict__ Cpart) {
  __shared__ __align__(16) ushort smem[2][4][4096];   // [db][arr][chunk*128*8] = 64 KB

  const int tid  = threadIdx.x;
  const int wave = tid >> 6;
  const int lane = tid & 63;
  const int row0 = blockIdx.x * 128;
  const int col0 = blockIdx.y * 128;
  const int ktb  = blockIdx.z * KQ;
  const int wm0  = (wave >> 1) * 64;
  const int wn0  = (wave & 1) * 64;
  const int ln31 = lane & 31;
  const int half = lane >> 5;            // 0/1

  floatx16 acc[2][2] = {};

  // wave w stages array w; one stage = one K32 tile (128 rows x 32 k = 8 KB)
  // seg s fills chunk = s>>1, rows (s&1)*64 + lane.
  auto stage = [&](int stg, int db) {
    const int kt    = ktb + stg;
    const int tap   = kt >> 4;
    const int itile = kt & 15;
    const ushort* gb;
    if (wave == 0)      gb = Ah + ((size_t)itile * SP + row0 + tap) * 32;
    else if (wave == 1) gb = Al + ((size_t)itile * SP + row0 + tap) * 32;
    else if (wave == 2) gb = Bh + ((size_t)kt * D + col0) * 32;
    else                gb = Bl + ((size_t)kt * D + col0) * 32;
    ushort* lb = &smem[db][wave][0];
#pragma unroll
    for (int seg = 0; seg < 8; ++seg) {
      const int r = (seg & 1) * 64 + lane;
      const int c = seg >> 1;
      gload16(gb + (size_t)r * 32 + c * 8, lb + seg * 512);
    }
  };

  stage(0, 0);

  for (int p = 0; p < KQ; ++p) {
    const int db = p & 1;
    __syncthreads();                     // drains this buffer's loads
    if (p + 1 < KQ) stage(p + 1, db ^ 1);

    const ushort* Ahs = &smem[db][0][0];
    const ushort* Als = &smem[db][1][0];
    const ushort* Bhs = &smem[db][2][0];
    const ushort* Bls = &smem[db][3][0];
#pragma unroll
    for (int sub = 0; sub < 2; ++sub) {
      const int cc = sub * 2 + half;     // k16-half chunk, per lane-half
      short8 ah[2], al2[2], bh[2], bl2[2];
#pragma unroll
      for (int mf = 0; mf < 2; ++mf) {
        const int off = (cc * 128 + wm0 + mf * 32 + ln31) * 8;
        ah[mf]  = *(const short8*)&Ahs[off];
        al2[mf] = *(const short8*)&Als[off];
      }
#pragma unroll
      for (int nf = 0; nf < 2; ++nf) {
        const int off = (cc * 128 + wn0 + nf * 32 + ln31) * 8;
        bh[nf]  = *(const short8*)&Bhs[off];
        bl2[nf] = *(const short8*)&Bls[off];
      }
#pragma unroll
      for (int mf = 0; mf < 2; ++mf)
#pragma unroll
        for (int nf = 0; nf < 2; ++nf) {
          acc[mf][nf] = __builtin_amdgcn_mfma_f32_32x32x16_bf16(ah[mf],  bh[nf],  acc[mf][nf], 0, 0, 0);
          acc[mf][nf] = __builtin_amdgcn_mfma_f32_32x32x16_bf16(ah[mf],  bl2[nf], acc[mf][nf], 0, 0, 0);
          acc[mf][nf] = __builtin_amdgcn_mfma_f32_32x32x16_bf16(al2[mf], bh[nf],  acc[mf][nf], 0, 0, 0);
        }
    }
  }

  float* C = Cpart + (size_t)blockIdx.z * S * D;
#pragma unroll
  for (int mf = 0; mf < 2; ++mf)
#pragma unroll
    for (int nf = 0; nf < 2; ++nf) {
      const int col = col0 + wn0 + nf * 32 + ln31;
#pragma unroll
      for (int reg = 0; reg < 16; ++reg) {
        const int row = row0 + wm0 + mf * 32 + (reg & 3) + 8 * (reg >> 2) + 4 * half;
        C[(size_t)row * D + col] = acc[mf][nf][reg];
      }
    }
}

// ---------------------------------------------------------------------------
// (sum of 4 partials + conv_bias) -> LayerNorm -> ReLU -> bf16 hi/lo packed.
// Fixed reduction order (z0+z1)+(z2+z3) -> deterministic.
// ---------------------------------------------------------------------------
__device__ inline void load8(const float* p, int lane, float o[8]) {
  const float4 a = ((const float4*)p)[2 * lane];
  const float4 b = ((const float4*)p)[2 * lane + 1];
  o[0] = a.x; o[1] = a.y; o[2] = a.z; o[3] = a.w;
  o[4] = b.x; o[5] = b.y; o[6] = b.z; o[7] = b.w;
}

__global__ __launch_bounds__(256) void ln_relu_pack_kernel(
    const float* __restrict__ Xp, const float* __restrict__ cb,
    const float* __restrict__ gam, const float* __restrict__ bet,
    ushort* __restrict__ th, ushort* __restrict__ tl) {
  const int wave = threadIdx.x >> 6;
  const int lane = threadIdx.x & 63;
  const int s = blockIdx.x * 4 + wave;
  float v[8], x1[8], x2[8], x3[8], bi[8];
  load8(Xp + (size_t)s * D, lane, v);
  load8(Xp + (size_t)S * D + (size_t)s * D, lane, x1);
  load8(Xp + 2 * (size_t)S * D + (size_t)s * D, lane, x2);
  load8(Xp + 3 * (size_t)S * D + (size_t)s * D, lane, x3);
  load8(cb, lane, bi);
#pragma unroll
  for (int i = 0; i < 8; ++i) v[i] = ((v[i] + x1[i]) + (x2[i] + x3[i])) + bi[i];
  float sum = 0.f;
#pragma unroll
  for (int i = 0; i < 8; ++i) sum += v[i];
#pragma unroll
  for (int off = 32; off > 0; off >>= 1) sum += __shfl_xor(sum, off);
  const float m = sum * (1.0f / D);
  float sq = 0.f;
#pragma unroll
  for (int i = 0; i < 8; ++i) { v[i] -= m; sq += v[i] * v[i]; }
#pragma unroll
  for (int off = 32; off > 0; off >>= 1) sq += __shfl_xor(sq, off);
  const float rs = rsqrtf(sq * (1.0f / D) + EPSLN);
  float gg[8], bt[8];
  load8(gam, lane, gg);
  load8(bet, lane, bt);
  short8 h8, l8;
#pragma unroll
  for (int i = 0; i < 8; ++i) {
    const float y = fmaxf(v[i] * rs * gg[i] + bt[i], 0.0f);
    const ushort hi = f2bf(y);
    h8[i] = (short)hi;
    l8[i] = (short)f2bf(y - bf2f(hi));
  }
  const size_t base = ((size_t)(lane >> 2) * SP + (s + 1)) * 32 + (size_t)(lane & 3) * 8;
  *(short8*)(th + base) = h8;
  *(short8*)(tl + base) = l8;
}

// ---------------------------------------------------------------------------
// (sum of 4 partials + bias) -> LN -> ReLU -> dot(lw) -> relu -> floor(p+0.5)
// ---------------------------------------------------------------------------
__global__ __launch_bounds__(256) void ln2_pred_kernel(
    const float* __restrict__ Xp, const float* __restrict__ cb,
    const float* __restrict__ gam, const float* __restrict__ bet,
    const float* __restrict__ lw, const float* __restrict__ lb,
    int* __restrict__ dur) {
  const int wave = threadIdx.x >> 6;
  const int lane = threadIdx.x & 63;
  const int s = blockIdx.x * 4 + wave;
  float v[8], x1[8], x2[8], x3[8], bi[8];
  load8(Xp + (size_t)s * D, lane, v);
  load8(Xp + (size_t)S * D + (size_t)s * D, lane, x1);
  load8(Xp + 2 * (size_t)S * D + (size_t)s * D, lane, x2);
  load8(Xp + 3 * (size_t)S * D + (size_t)s * D, lane, x3);
  load8(cb, lane, bi);
#pragma unroll
  for (int i = 0; i < 8; ++i) v[i] = ((v[i] + x1[i]) + (x2[i] + x3[i])) + bi[i];
  float sum = 0.f;
#pragma unroll
  for (int i = 0; i < 8; ++i) sum += v[i];
#pragma unroll
  for (int off = 32; off > 0; off >>= 1) sum += __shfl_xor(sum, off);
  const float m = sum * (1.0f / D);
  float sq = 0.f;
#pragma unroll
  for (int i = 0; i < 8; ++i) { v[i] -= m; sq += v[i] * v[i]; }
#pragma unroll
  for (int off = 32; off > 0; off >>= 1) sq += __shfl_xor(sq, off);
  const float rs = rsqrtf(sq * (1.0f / D) + EPSLN);
  float gg[8], bt[8], ww[8];
  load8(gam, lane, gg);
  load8(bet, lane, bt);
  load8(lw, lane, ww);
  float d = 0.f;
#pragma unroll
  for (int i = 0; i < 8; ++i) {
    const float y = fmaxf(v[i] * rs * gg[i] + bt[i], 0.0f);
    d += y * ww[i];
  }
#pragma unroll
  for (int off = 32; off > 0; off >>= 1) d += __shfl_xor(d, off);
  if (lane == 0) {
    const float p = fmaxf(d + lb[0], 0.0f);
    dur[s] = (int)floorf(p + 0.5f);
  }
}

// ---------------------------------------------------------------------------
// Inclusive scan of S=4096 ints with ONE wave.
// ---------------------------------------------------------------------------
__global__ __launch_bounds__(64) void scan_kernel(const int* __restrict__ dur,
                                                  int* __restrict__ cum) {
  const int lane = threadIdx.x;
  const int4* src = (const int4*)dur + (size_t)lane * 16;
  int4 v[16];
  int run = 0;
#pragma unroll
  for (int i = 0; i < 16; ++i) {
    int4 d = src[i];
    d.x += run; d.y += d.x; d.z += d.y; d.w += d.z;
    run = d.w;
    v[i] = d;
  }
  int sc = run;
#pragma unroll
  for (int off = 1; off < 64; off <<= 1) {
    const int n = __shfl_up(sc, off);
    if (lane >= off) sc += n;
  }
  const int base = sc - run;
  int4* dst = (int4*)cum + (size_t)lane * 16;
#pragma unroll
  for (int i = 0; i < 16; ++i) {
    int4 d = v[i];
    d.x += base; d.y += base; d.z += base; d.w += base;
    dst[i] = d;
  }
}

// ---------------------------------------------------------------------------
// Length-regulate gather. 2 frames per 256-thread block.
// ---------------------------------------------------------------------------
__global__ __launch_bounds__(256) void gather_kernel(
    const float* __restrict__ enc, const int* __restrict__ cum,
    float* __restrict__ out0, float* __restrict__ out1) {
  const int half = threadIdx.x >> 7;
  const int d4   = (threadIdx.x & 127) << 2;
  const int t    = blockIdx.x * 2 + half;
  const int total = cum[S - 1];

  int lo = 0, hi = S;
  while (lo < hi) {
    const int mid = (lo + hi) >> 1;
    if (cum[mid] <= t) lo = mid + 1; else hi = mid;
  }
  const int idx = (lo < S) ? lo : (S - 1);

  float4 v = make_float4(0.f, 0.f, 0.f, 0.f);
  if (t < total) v = *(const float4*)(enc + (size_t)idx * D + d4);
  *(float4*)(out0 + (size_t)t * D + d4) = v;

  if ((threadIdx.x & 127) == 0) out1[t] = (float)(t + 1);
}

// ---------------------------------------------------------------------------
extern "C" void kernel_launch(void* const* d_in, const int* in_sizes, int n_in,
                              void* d_out, int out_size, void* d_ws, size_t ws_size,
                              hipStream_t stream) {
  const float* enc = (const float*)d_in[0];
  const float* w1  = (const float*)d_in[1];
  const float* cb1 = (const float*)d_in[2];
  const float* g1  = (const float*)d_in[3];
  const float* be1 = (const float*)d_in[4];
  const float* w2  = (const float*)d_in[5];
  const float* cb2 = (const float*)d_in[6];
  const float* g2  = (const float*)d_in[7];
  const float* be2 = (const float*)d_in[8];
  const float* lw  = (const float*)d_in[9];
  const float* lb  = (const float*)d_in[10];

  float* out0 = (float*)d_out;                 // [MAXOUT, D]
  float* out1 = out0 + (size_t)MAXOUT * D;     // [MAXOUT]

  const size_t NP = (size_t)NIT * SP * 32;     // packed activation elems
  const size_t NB = (size_t)NKT * D * 32;      // packed weight elems
  ushort* Xph = (ushort*)d_ws;
  ushort* Xpl = Xph + NP;
  ushort* T1h = Xpl + NP;
  ushort* T1l = T1h + NP;
  ushort* B1h = T1l + NP;
  ushort* B1l = B1h + NB;
  ushort* B2h = B1l + NB;
  ushort* B2l = B2h + NB;
  float*  t0  = (float*)(B2l + NB);            // KSPLIT x S*D fp32 partials
  int*   dur  = (int*)(t0 + (size_t)KSPLIT * S * D);
  int*   cum  = dur + S;

  pack_all_kernel<<<NB0 + 2 * NB1 + NB3, 256, 0, stream>>>(
      enc, w1, w2, Xph, Xpl, B1h, B1l, B2h, B2l, T1h, T1l);
  gemm_mfma_kernel<<<dim3(S / 128, D / 128, KSPLIT), 256, 0, stream>>>(
      Xph, Xpl, B1h, B1l, t0);
  ln_relu_pack_kernel<<<S / 4, 256, 0, stream>>>(t0, cb1, g1, be1, T1h, T1l);
  gemm_mfma_kernel<<<dim3(S / 128, D / 128, KSPLIT), 256, 0, stream>>>(
      T1h, T1l, B2h, B2l, t0);
  ln2_pred_kernel<<<S / 4, 256, 0, stream>>>(t0, cb2, g2, be2, lw, lb, dur);
  scan_kernel<<<1, 64, 0, stream>>>(dur, cum);
  gather_kernel<<<MAXOUT / 2, 256, 0, stream>>>(enc, cum, out0, out1);
}

// Round 6
// 170.487 us; speedup vs baseline: 1.0494x; 1.0494x over previous
//
#include <hip/hip_runtime.h>

#define S      4096
#define D      512
#define KWIN   3
#define SP     (S + 2)          // zero-padded rows: g = s + tap, g in [0, S+1]
#define MAXOUT 16384
#define EPSLN  1e-5f
#define NIT    16               // i-tiles per tap (512/32)
#define NKT    48               // total K tiles of 32 (1536/32)
#define KSPLIT 4
#define KQ     (NKT / KSPLIT)   // 12 K32-stages per block

typedef __attribute__((ext_vector_type(8)))  short short8;
typedef __attribute__((ext_vector_type(16))) float floatx16;

__device__ inline ushort f2bf(float x) {
  union { float f; unsigned u; } v; v.f = x;
  unsigned r = v.u + 0x7fffu + ((v.u >> 16) & 1u);
  return (ushort)(r >> 16);
}
__device__ inline float bf2f(ushort h) {
  union { float f; unsigned u; } v; v.u = ((unsigned)h) << 16;
  return v.f;
}

// ---------------------------------------------------------------------------
// One launch does ALL packing (vectorized short8 writes):
//  region 0: enc -> Xp hi/lo [NIT][SP][32], zero pad rows   (1025 blocks)
//  region 1: w1  -> B1 hi/lo [NKT][D][32]                   (384 blocks)
//  region 2: w2  -> B2 hi/lo                                (384 blocks)
//  region 3: zero T1 pad rows                               (4 blocks)
// ---------------------------------------------------------------------------
#define NB0 1025
#define NB1 384
#define NB3 4

__device__ inline void wpack8(const float* __restrict__ w, ushort* __restrict__ bh,
                              ushort* __restrict__ bl, int q) {
  const int kk0 = (q & 3) * 8;
  const int o   = (q >> 2) & 511;
  const int it  = (q >> 11) & 15;
  const int k   = q >> 15;             // 0..2
  short8 h8, l8;
#pragma unroll
  for (int j = 0; j < 8; ++j) {
    const float v = w[o * (D * KWIN) + (it * 32 + kk0 + j) * KWIN + k];
    const ushort hi = f2bf(v);
    h8[j] = (short)hi;
    l8[j] = (short)f2bf(v - bf2f(hi));
  }
  *(short8*)(bh + (size_t)q * 8) = h8;   // dst == q*8 exactly (layout identity)
  *(short8*)(bl + (size_t)q * 8) = l8;
}

__global__ __launch_bounds__(256) void pack_all_kernel(
    const float* __restrict__ x, const float* __restrict__ w1,
    const float* __restrict__ w2, ushort* __restrict__ Xph,
    ushort* __restrict__ Xpl, ushort* __restrict__ B1h, ushort* __restrict__ B1l,
    ushort* __restrict__ B2h, ushort* __restrict__ B2l,
    ushort* __restrict__ T1h, ushort* __restrict__ T1l) {
  const int b = blockIdx.x;
  if (b < NB0) {
    const int t = b * 256 + threadIdx.x;          // over SP*64 groups of 8
    if (t >= SP * 64) return;
    const int g  = t >> 6;
    const int i0 = (t & 63) * 8;
    float vv[8] = {};
    if (g > 0 && g < SP - 1) {
      const float4 v0 = *(const float4*)(x + (size_t)(g - 1) * D + i0);
      const float4 v1 = *(const float4*)(x + (size_t)(g - 1) * D + i0 + 4);
      vv[0] = v0.x; vv[1] = v0.y; vv[2] = v0.z; vv[3] = v0.w;
      vv[4] = v1.x; vv[5] = v1.y; vv[6] = v1.z; vv[7] = v1.w;
    }
    short8 h8, l8;
#pragma unroll
    for (int j = 0; j < 8; ++j) {
      const ushort hi = f2bf(vv[j]);
      h8[j] = (short)hi;
      l8[j] = (short)f2bf(vv[j] - bf2f(hi));
    }
    const size_t dst = ((size_t)(i0 >> 5) * SP + g) * 32 + (i0 & 31);
    *(short8*)(Xph + dst) = h8;
    *(short8*)(Xpl + dst) = l8;
  } else if (b < NB0 + NB1) {
    wpack8(w1, B1h, B1l, (b - NB0) * 256 + threadIdx.x);
  } else if (b < NB0 + 2 * NB1) {
    wpack8(w2, B2h, B2l, (b - NB0 - NB1) * 256 + threadIdx.x);
  } else {
    const int idx = (b - NB0 - 2 * NB1) * 256 + threadIdx.x;   // 0..1023
    const int c   = idx >> 6;
    const int rr  = (idx >> 5) & 1;
    const int col = idx & 31;
    const size_t off = ((size_t)c * SP + (rr ? (SP - 1) : 0)) * 32 + col;
    T1h[off] = 0;
    T1l[off] = 0;
  }
}

// ---------------------------------------------------------------------------
// MFMA GEMM, fp32-accurate bf16 hi/lo (hh+hl+lh), 32x32x16 MFMA.
// Block tile 128x128, 4 waves in 2x2, wave tile 64x64 (2x2 accs of 32x32).
// Split-K=4 via gridDim.z -> 512 blocks = 2 blocks/CU (__launch_bounds 256,2)
// so a partner block hides each stage's barrier/vmcnt drain.
// Double-buffered LDS (64 KB), one barrier per K32 stage.
// Row-major LDS [row][32] + XOR chunk swizzle c = (lane&3)^(r&3):
//  - staging per seg is one contiguous 1 KB block (coalesced; the swizzle
//    only permutes 16B chunks inside 64-B rows),
//  - frag reads spread over all 8 (parity,chunk) bank groups -> conflict-free.
// Numerics identical to the round-4 kernel (absmax 0).
// ---------------------------------------------------------------------------
__device__ inline void gload16(const void* g, void* l) {
  __builtin_amdgcn_global_load_lds((const __attribute__((address_space(1))) void*)g,
                                   (__attribute__((address_space(3))) void*)l,
                                   16, 0, 0);
}

__global__ __launch_bounds__(256, 2) void gemm_mfma_kernel(
    const ushort* __restrict__ Ah, const ushort* __restrict__ Al,
    const ushort* __restrict__ Bh, const ushort* __restrict__ Bl,
    float* __restrict__ Cpart) {
  __shared__ __align__(16) ushort smem[2][4][128 * 32];   // 64 KB

  const int tid  = threadIdx.x;
  const int wave = tid >> 6;
  const int lane = tid & 63;
  const int row0 = blockIdx.x * 128;
  const int col0 = blockIdx.y * 128;
  const int ktb  = blockIdx.z * KQ;
  const int wm0  = (wave >> 1) * 64;
  const int wn0  = (wave & 1) * 64;
  const int ln31 = lane & 31;
  const int half = lane >> 5;            // 0/1

  floatx16 acc[2][2] = {};

  // wave w stages array w; one stage = one K32 tile = 8 KB = 8 segs of 1 KB
  auto stage = [&](int stg, int db) {
    const int kt    = ktb + stg;
    const int tap   = kt >> 4;
    const int itile = kt & 15;
    const ushort* gb;
    if (wave == 0)      gb = Ah + ((size_t)itile * SP + row0 + tap) * 32;
    else if (wave == 1) gb = Al + ((size_t)itile * SP + row0 + tap) * 32;
    else if (wave == 2) gb = Bh + ((size_t)kt * D + col0) * 32;
    else                gb = Bl + ((size_t)kt * D + col0) * 32;
    ushort* lb = &smem[db][wave][0];
#pragma unroll
    for (int seg = 0; seg < 8; ++seg) {
      const int r = seg * 16 + (lane >> 2);          // row 0..127
      const int c = (lane & 3) ^ (r & 3);            // swizzled source chunk
      gload16(gb + (size_t)r * 32 + c * 8, lb + seg * 512);
    }
  };

  stage(0, 0);

  for (int p = 0; p < KQ; ++p) {
    const int db = p & 1;
    __syncthreads();                     // drains this buffer's loads
    if (p + 1 < KQ) stage(p + 1, db ^ 1);

#pragma unroll
    for (int sub = 0; sub < 2; ++sub) {
      const int cchunk = sub * 2 + half;
      short8 ah[2], al2[2], bh[2], bl2[2];
#pragma unroll
      for (int mf = 0; mf < 2; ++mf) {
        const int r  = wm0 + mf * 32 + ln31;
        const int cs = cchunk ^ (r & 3);
        const int off = r * 32 + cs * 8;
        ah[mf]  = *(const short8*)&smem[db][0][off];
        al2[mf] = *(const short8*)&smem[db][1][off];
      }
#pragma unroll
      for (int nf = 0; nf < 2; ++nf) {
        const int r  = wn0 + nf * 32 + ln31;
        const int cs = cchunk ^ (r & 3);
        const int off = r * 32 + cs * 8;
        bh[nf]  = *(const short8*)&smem[db][2][off];
        bl2[nf] = *(const short8*)&smem[db][3][off];
      }
#pragma unroll
      for (int mf = 0; mf < 2; ++mf)
#pragma unroll
        for (int nf = 0; nf < 2; ++nf) {
          acc[mf][nf] = __builtin_amdgcn_mfma_f32_32x32x16_bf16(ah[mf],  bh[nf],  acc[mf][nf], 0, 0, 0);
          acc[mf][nf] = __builtin_amdgcn_mfma_f32_32x32x16_bf16(ah[mf],  bl2[nf], acc[mf][nf], 0, 0, 0);
          acc[mf][nf] = __builtin_amdgcn_mfma_f32_32x32x16_bf16(al2[mf], bh[nf],  acc[mf][nf], 0, 0, 0);
        }
    }
  }

  float* C = Cpart + (size_t)blockIdx.z * S * D;
#pragma unroll
  for (int mf = 0; mf < 2; ++mf)
#pragma unroll
    for (int nf = 0; nf < 2; ++nf) {
      const int col = col0 + wn0 + nf * 32 + ln31;
#pragma unroll
      for (int reg = 0; reg < 16; ++reg) {
        const int row = row0 + wm0 + mf * 32 + (reg & 3) + 8 * (reg >> 2) + 4 * half;
        C[(size_t)row * D + col] = acc[mf][nf][reg];
      }
    }
}

// ---------------------------------------------------------------------------
// (sum of 4 partials + conv_bias) -> LayerNorm -> ReLU -> bf16 hi/lo packed.
// Fixed reduction order (z0+z1)+(z2+z3) -> deterministic.
// ---------------------------------------------------------------------------
__device__ inline void load8(const float* p, int lane, float o[8]) {
  const float4 a = ((const float4*)p)[2 * lane];
  const float4 b = ((const float4*)p)[2 * lane + 1];
  o[0] = a.x; o[1] = a.y; o[2] = a.z; o[3] = a.w;
  o[4] = b.x; o[5] = b.y; o[6] = b.z; o[7] = b.w;
}

__global__ __launch_bounds__(256) void ln_relu_pack_kernel(
    const float* __restrict__ Xp, const float* __restrict__ cb,
    const float* __restrict__ gam, const float* __restrict__ bet,
    ushort* __restrict__ th, ushort* __restrict__ tl) {
  const int wave = threadIdx.x >> 6;
  const int lane = threadIdx.x & 63;
  const int s = blockIdx.x * 4 + wave;
  float v[8], x1[8], x2[8], x3[8], bi[8];
  load8(Xp + (size_t)s * D, lane, v);
  load8(Xp + (size_t)S * D + (size_t)s * D, lane, x1);
  load8(Xp + 2 * (size_t)S * D + (size_t)s * D, lane, x2);
  load8(Xp + 3 * (size_t)S * D + (size_t)s * D, lane, x3);
  load8(cb, lane, bi);
#pragma unroll
  for (int i = 0; i < 8; ++i) v[i] = ((v[i] + x1[i]) + (x2[i] + x3[i])) + bi[i];
  float sum = 0.f;
#pragma unroll
  for (int i = 0; i < 8; ++i) sum += v[i];
#pragma unroll
  for (int off = 32; off > 0; off >>= 1) sum += __shfl_xor(sum, off);
  const float m = sum * (1.0f / D);
  float sq = 0.f;
#pragma unroll
  for (int i = 0; i < 8; ++i) { v[i] -= m; sq += v[i] * v[i]; }
#pragma unroll
  for (int off = 32; off > 0; off >>= 1) sq += __shfl_xor(sq, off);
  const float rs = rsqrtf(sq * (1.0f / D) + EPSLN);
  float gg[8], bt[8];
  load8(gam, lane, gg);
  load8(bet, lane, bt);
  short8 h8, l8;
#pragma unroll
  for (int i = 0; i < 8; ++i) {
    const float y = fmaxf(v[i] * rs * gg[i] + bt[i], 0.0f);
    const ushort hi = f2bf(y);
    h8[i] = (short)hi;
    l8[i] = (short)f2bf(y - bf2f(hi));
  }
  const size_t base = ((size_t)(lane >> 2) * SP + (s + 1)) * 32 + (size_t)(lane & 3) * 8;
  *(short8*)(th + base) = h8;
  *(short8*)(tl + base) = l8;
}

// ---------------------------------------------------------------------------
// (sum of 4 partials + bias) -> LN -> ReLU -> dot(lw) -> relu -> floor(p+0.5)
// ---------------------------------------------------------------------------
__global__ __launch_bounds__(256) void ln2_pred_kernel(
    const float* __restrict__ Xp, const float* __restrict__ cb,
    const float* __restrict__ gam, const float* __restrict__ bet,
    const float* __restrict__ lw, const float* __restrict__ lb,
    int* __restrict__ dur) {
  const int wave = threadIdx.x >> 6;
  const int lane = threadIdx.x & 63;
  const int s = blockIdx.x * 4 + wave;
  float v[8], x1[8], x2[8], x3[8], bi[8];
  load8(Xp + (size_t)s * D, lane, v);
  load8(Xp + (size_t)S * D + (size_t)s * D, lane, x1);
  load8(Xp + 2 * (size_t)S * D + (size_t)s * D, lane, x2);
  load8(Xp + 3 * (size_t)S * D + (size_t)s * D, lane, x3);
  load8(cb, lane, bi);
#pragma unroll
  for (int i = 0; i < 8; ++i) v[i] = ((v[i] + x1[i]) + (x2[i] + x3[i])) + bi[i];
  float sum = 0.f;
#pragma unroll
  for (int i = 0; i < 8; ++i) sum += v[i];
#pragma unroll
  for (int off = 32; off > 0; off >>= 1) sum += __shfl_xor(sum, off);
  const float m = sum * (1.0f / D);
  float sq = 0.f;
#pragma unroll
  for (int i = 0; i < 8; ++i) { v[i] -= m; sq += v[i] * v[i]; }
#pragma unroll
  for (int off = 32; off > 0; off >>= 1) sq += __shfl_xor(sq, off);
  const float rs = rsqrtf(sq * (1.0f / D) + EPSLN);
  float gg[8], bt[8], ww[8];
  load8(gam, lane, gg);
  load8(bet, lane, bt);
  load8(lw, lane, ww);
  float d = 0.f;
#pragma unroll
  for (int i = 0; i < 8; ++i) {
    const float y = fmaxf(v[i] * rs * gg[i] + bt[i], 0.0f);
    d += y * ww[i];
  }
#pragma unroll
  for (int off = 32; off > 0; off >>= 1) d += __shfl_xor(d, off);
  if (lane == 0) {
    const float p = fmaxf(d + lb[0], 0.0f);
    dur[s] = (int)floorf(p + 0.5f);
  }
}

// ---------------------------------------------------------------------------
// Inclusive scan of S=4096 ints with ONE wave.
// ---------------------------------------------------------------------------
__global__ __launch_bounds__(64) void scan_kernel(const int* __restrict__ dur,
                                                  int* __restrict__ cum) {
  const int lane = threadIdx.x;
  const int4* src = (const int4*)dur + (size_t)lane * 16;
  int4 v[16];
  int run = 0;
#pragma unroll
  for (int i = 0; i < 16; ++i) {
    int4 d = src[i];
    d.x += run; d.y += d.x; d.z += d.y; d.w += d.z;
    run = d.w;
    v[i] = d;
  }
  int sc = run;
#pragma unroll
  for (int off = 1; off < 64; off <<= 1) {
    const int n = __shfl_up(sc, off);
    if (lane >= off) sc += n;
  }
  const int base = sc - run;
  int4* dst = (int4*)cum + (size_t)lane * 16;
#pragma unroll
  for (int i = 0; i < 16; ++i) {
    int4 d = v[i];
    d.x += base; d.y += base; d.z += base; d.w += base;
    dst[i] = d;
  }
}

// ---------------------------------------------------------------------------
// Length-regulate gather. 2 frames per 256-thread block.
// ---------------------------------------------------------------------------
__global__ __launch_bounds__(256) void gather_kernel(
    const float* __restrict__ enc, const int* __restrict__ cum,
    float* __restrict__ out0, float* __restrict__ out1) {
  const int half = threadIdx.x >> 7;
  const int d4   = (threadIdx.x & 127) << 2;
  const int t    = blockIdx.x * 2 + half;
  const int total = cum[S - 1];

  int lo = 0, hi = S;
  while (lo < hi) {
    const int mid = (lo + hi) >> 1;
    if (cum[mid] <= t) lo = mid + 1; else hi = mid;
  }
  const int idx = (lo < S) ? lo : (S - 1);

  float4 v = make_float4(0.f, 0.f, 0.f, 0.f);
  if (t < total) v = *(const float4*)(enc + (size_t)idx * D + d4);
  *(float4*)(out0 + (size_t)t * D + d4) = v;

  if ((threadIdx.x & 127) == 0) out1[t] = (float)(t + 1);
}

// ---------------------------------------------------------------------------
extern "C" void kernel_launch(void* const* d_in, const int* in_sizes, int n_in,
                              void* d_out, int out_size, void* d_ws, size_t ws_size,
                              hipStream_t stream) {
  const float* enc = (const float*)d_in[0];
  const float* w1  = (const float*)d_in[1];
  const float* cb1 = (const float*)d_in[2];
  const float* g1  = (const float*)d_in[3];
  const float* be1 = (const float*)d_in[4];
  const float* w2  = (const float*)d_in[5];
  const float* cb2 = (const float*)d_in[6];
  const float* g2  = (const float*)d_in[7];
  const float* be2 = (const float*)d_in[8];
  const float* lw  = (const float*)d_in[9];
  const float* lb  = (const float*)d_in[10];

  float* out0 = (float*)d_out;                 // [MAXOUT, D]
  float* out1 = out0 + (size_t)MAXOUT * D;     // [MAXOUT]

  const size_t NP = (size_t)NIT * SP * 32;     // packed activation elems
  const size_t NB = (size_t)NKT * D * 32;      // packed weight elems
  ushort* Xph = (ushort*)d_ws;
  ushort* Xpl = Xph + NP;
  ushort* T1h = Xpl + NP;
  ushort* T1l = T1h + NP;
  ushort* B1h = T1l + NP;
  ushort* B1l = B1h + NB;
  ushort* B2h = B1l + NB;
  ushort* B2l = B2h + NB;
  float*  t0  = (float*)(B2l + NB);            // KSPLIT x S*D fp32 partials
  int*   dur  = (int*)(t0 + (size_t)KSPLIT * S * D);
  int*   cum  = dur + S;

  pack_all_kernel<<<NB0 + 2 * NB1 + NB3, 256, 0, stream>>>(
      enc, w1, w2, Xph, Xpl, B1h, B1l, B2h, B2l, T1h, T1l);
  gemm_mfma_kernel<<<dim3(S / 128, D / 128, KSPLIT), 256, 0, stream>>>(
      Xph, Xpl, B1h, B1l, t0);
  ln_relu_pack_kernel<<<S / 4, 256, 0, stream>>>(t0, cb1, g1, be1, T1h, T1l);
  gemm_mfma_kernel<<<dim3(S / 128, D / 128, KSPLIT), 256, 0, stream>>>(
      T1h, T1l, B2h, B2l, t0);
  ln2_pred_kernel<<<S / 4, 256, 0, stream>>>(t0, cb2, g2, be2, lw, lb, dur);
  scan_kernel<<<1, 64, 0, stream>>>(dur, cum);
  gather_kernel<<<MAXOUT / 2, 256, 0, stream>>>(enc, cum, out0, out1);
}